// Round 8
// baseline (328.371 us; speedup 1.0000x reference)
//
#include <hip/hip_runtime.h>
#include <hip/hip_bf16.h>
#include <cstddef>

#define NN 100000
#define EE 1600000
#define NPB 128                 // nodes per bucket
#define NB  782                 // ceil(NN / NPB)
#define ECH 4096                // edges per scatter chunk
#define NCH 391                 // ceil(EE / ECH)
#define CAP 4096                // bucket slot capacity (mean 2048, sigma ~45 -> 45-sigma margin)

typedef __attribute__((ext_vector_type(8))) short bf16x8;
typedef __attribute__((ext_vector_type(8))) unsigned short u16x8;
typedef __attribute__((ext_vector_type(4))) float f32x4;

#define YTS 72                  // LDS ushort stride for epilogue tiles (144 B rows)

static inline int ceil_div(int a, int b){ return (a + b - 1) / b; }

__device__ inline unsigned short f2bf(float f){
  union { float f; unsigned u; } v; v.f = f;
  unsigned r = (v.u + 0x7fff + ((v.u >> 16) & 1)) >> 16;   // RNE
  return (unsigned short)r;
}
__device__ inline float bf2f(unsigned short s){
  union { unsigned u; float f; } v; v.u = ((unsigned)s) << 16;
  return v.f;
}

// ---- fused prep: wcat bf16, wee = We1@We0, b1e = We1@be0+be1, bias0 = bl0+be0, cur = 0 ----
#define PRE_W (128 * 192)
#define PRE_E (PRE_W + 16 * 64)
#define PRE_B (PRE_E + 16)
#define PRE_C (PRE_B + 64)
#define PRE_N (PRE_C + NB)
__global__ void prep_all_kernel(const float* __restrict__ Wl0, const float* __restrict__ Wr0,
                                const float* __restrict__ We0, const float* __restrict__ bl0,
                                const float* __restrict__ be0, const float* __restrict__ We1,
                                const float* __restrict__ be1,
                                unsigned short* __restrict__ wcat, float* __restrict__ wee,
                                float* __restrict__ b1e, float* __restrict__ bias0,
                                int* __restrict__ cur){
  int idx = blockIdx.x * blockDim.x + threadIdx.x;
  if (idx < PRE_W){
    int n = idx / 192, k = idx % 192;
    float v;
    if (n < 64) v = (k < 128) ? Wl0[n * 128 + k] : 0.f;
    else        v = (k < 128) ? Wr0[(n - 64) * 128 + k] : We0[(n - 64) * 64 + (k - 128)];
    wcat[idx] = f2bf(v);
  } else if (idx < PRE_E){
    int j = idx - PRE_W;
    int i = j >> 6, c = j & 63;
    float s = 0.f;
    for (int k = 0; k < 64; k++) s += We1[i * 64 + k] * We0[k * 64 + c];
    wee[j] = s;
  } else if (idx < PRE_B){
    int i = idx - PRE_E;
    float s = be1[i];
    for (int k = 0; k < 64; k++) s += We1[i * 64 + k] * be0[k];
    b1e[i] = s;
  } else if (idx < PRE_C){
    int i = idx - PRE_B;
    bias0[i] = bl0[i] + be0[i];
  } else if (idx < PRE_N){
    cur[idx - PRE_C] = 0;
  }
}

// ---------------- bucketed edge scatter into fixed-capacity slots ----------------
__global__ __launch_bounds__(256) void escatter_kernel(const int* __restrict__ src,
                                                       const int* __restrict__ dst,
                                                       int* __restrict__ cur,
                                                       int* __restrict__ ebkt){
  __shared__ int lh[NB];
  __shared__ int lo[NB];
  int t = threadIdx.x;
  int e0 = blockIdx.x * ECH;
  int ne = EE - e0; if (ne > ECH) ne = ECH;
  for (int i = t; i < NB; i += 256) lh[i] = 0;
  __syncthreads();
  for (int i = t; i < ne; i += 256)
    atomicAdd(&lh[dst[e0 + i] >> 7], 1);
  __syncthreads();
  for (int i = t; i < NB; i += 256){
    int c = lh[i];
    lo[i] = c ? atomicAdd(&cur[i], c) : 0;
    lh[i] = 0;
  }
  __syncthreads();
  for (int i = t; i < ne; i += 256){
    int d = dst[e0 + i], b = d >> 7;
    int r = atomicAdd(&lh[b], 1);
    int p = lo[b] + r;
    if (p < CAP) ebkt[b * CAP + p] = ((d & 127) << 24) | src[e0 + i];
  }
}

// ---------------- per-bucket counting sort (in-place) -> padded CSR ----------------
__global__ __launch_bounds__(256) void bsort_kernel(
    const int* __restrict__ cur, int* __restrict__ ebkt,
    int* __restrict__ rs, int* __restrict__ deg){
  __shared__ int lraw[CAP];
  __shared__ int lout[CAP];
  __shared__ int lh[NPB];
  __shared__ int loff[NPB];
  __shared__ int lcur[NPB];
  const int t = threadIdx.x;
  const int b = blockIdx.x;
  const int e0 = b * CAP;
  int cnt = cur[b];
  if (cnt > CAP) cnt = CAP;
  for (int i = t; i < NPB; i += 256) lh[i] = 0;
  __syncthreads();
  for (int i = t; i < cnt; i += 256){
    int w = ebkt[e0 + i];
    lraw[i] = w;
    atomicAdd(&lh[((unsigned)w) >> 24], 1);
  }
  __syncthreads();
  {
    int v = (t < NPB) ? lh[t] : 0;
    int s = v;
    for (int off = 1; off < NPB; off <<= 1){
      int x = 0;
      if (t < NPB && t >= off) x = loff[t - off];
      __syncthreads();
      if (t < NPB) loff[t] = s;
      __syncthreads();
      if (t < NPB && t >= off) s += loff[t - off];
      __syncthreads();
    }
    if (t < NPB){ loff[t] = s - v; lcur[t] = s - v; }
  }
  __syncthreads();
  for (int i = t; i < cnt; i += 256){
    int w = lraw[i];
    int d = ((unsigned)w) >> 24;
    int pos = atomicAdd(&lcur[d], 1);
    lout[pos] = w & 0xFFFFFF;
  }
  __syncthreads();
  for (int i = t; i < cnt; i += 256) ebkt[e0 + i] = lout[i];
  if (t < NPB){
    int node = b * NPB + t;
    if (node < NN){
      rs[node]  = e0 + loff[t];
      deg[node] = lh[t];
    }
  }
}

// ---------------- layer-0 fused MFMA GEMM, LDS-overlay epilogue ----------------
// A_ext = [x_feat | mean(x_emb)] (64 x 192 bf16); Wcat 128x192 bf16.
// wave w: y0 cols w*16..+15, re0 cols w*16..+15 (both bf16 out). Also emits e (bf16).
// LDS: As (25.6 KB) overlaid by Ys+Rs (2 x 9.2 KB) after the MFMA loop.
__global__ __launch_bounds__(256, 4) void l0_gemm_kernel(
    const float* __restrict__ x_feat, const float* __restrict__ x_emb,
    const unsigned short* __restrict__ wcat,
    unsigned short* __restrict__ y0g, unsigned short* __restrict__ re0g,
    unsigned short* __restrict__ e_bf, int M){
  __shared__ unsigned short smem[64 * 200];                  // 25.6 KB shared pool
  unsigned short* As = smem;
  unsigned short* Ys = smem;                                 // overlay (As dead)
  unsigned short* Rs = smem + 64 * YTS;                      // +9216 ushorts
  const int t = threadIdx.x;
  const int row0 = blockIdx.x * 64;
  // ---- staging: 12 quads/thread, batched loads ----
  float4 tmpa[12], tmpb[12];
  #pragma unroll
  for (int k = 0; k < 12; k++){
    int idx = t + k * 256;
    int r = idx / 48, q = idx % 48;
    int row = row0 + r;
    float4 v = make_float4(0.f, 0.f, 0.f, 0.f);
    float4 u = make_float4(0.f, 0.f, 0.f, 0.f);
    if (row < M){
      if (q < 32) v = ((const float4*)x_feat)[(size_t)row * 32 + q];
      else {
        v = ((const float4*)x_emb)[(size_t)row * 32 + (q - 32)];
        u = ((const float4*)x_emb)[(size_t)row * 32 + 16 + (q - 32)];
      }
    }
    tmpa[k] = v; tmpb[k] = u;
  }
  #pragma unroll
  for (int k = 0; k < 12; k++){
    int idx = t + k * 256;
    int r = idx / 48, q = idx % 48;
    int row = row0 + r;
    float4 v = tmpa[k];
    if (q >= 32){
      float4 u = tmpb[k];
      v.x = 0.5f * (v.x + u.x); v.y = 0.5f * (v.y + u.y);
      v.z = 0.5f * (v.z + u.z); v.w = 0.5f * (v.w + u.w);
    }
    ushort4 s; s.x = f2bf(v.x); s.y = f2bf(v.y); s.z = f2bf(v.z); s.w = f2bf(v.w);
    *(ushort4*)&As[r * 200 + q * 4] = s;
    if (q >= 32 && row < M)
      *(ushort4*)&e_bf[(size_t)row * 64 + (q - 32) * 4] = s;
  }
  // ---- B fragments (reg-resident, uniform across waves) ----
  const int w = t >> 6, l = t & 63;
  const int lm = l & 15, quad = l >> 4;
  bf16x8 bfr0[6], bfr1[6];
  {
    int n0 = w * 16 + lm;          // y0 tile w
    int n1 = 64 + w * 16 + lm;     // re0 tile w
    #pragma unroll
    for (int ks = 0; ks < 6; ks++){
      bfr0[ks] = *(const bf16x8*)&wcat[n0 * 192 + ks * 32 + quad * 8];
      bfr1[ks] = *(const bf16x8*)&wcat[n1 * 192 + ks * 32 + quad * 8];
    }
  }
  __syncthreads();
  f32x4 a0[4], a1[4];
  #pragma unroll
  for (int rg = 0; rg < 4; rg++){
    bf16x8 af[6];
    #pragma unroll
    for (int ks = 0; ks < 6; ks++)
      af[ks] = *(const bf16x8*)&As[(rg * 16 + lm) * 200 + ks * 32 + quad * 8];
    f32x4 acc0 = {0.f, 0.f, 0.f, 0.f};
    f32x4 acc1 = {0.f, 0.f, 0.f, 0.f};
    #pragma unroll
    for (int ks = 0; ks < 6; ks++){
      acc0 = __builtin_amdgcn_mfma_f32_16x16x32_bf16(af[ks], bfr0[ks], acc0, 0, 0, 0);
      acc1 = __builtin_amdgcn_mfma_f32_16x16x32_bf16(af[ks], bfr1[ks], acc1, 0, 0, 0);
    }
    a0[rg] = acc0; a1[rg] = acc1;
  }
  __syncthreads();   // all waves done reading As -> safe to overlay
  // deposit C fragments (col=lm, row=quad*4+r) as bf16
  #pragma unroll
  for (int rg = 0; rg < 4; rg++){
    #pragma unroll
    for (int r = 0; r < 4; r++){
      int lrow = rg * 16 + quad * 4 + r;
      Ys[lrow * YTS + w * 16 + lm] = f2bf(a0[rg][r]);
      Rs[lrow * YTS + w * 16 + lm] = f2bf(a1[rg][r]);
    }
  }
  __syncthreads();
  // coalesced writeback: 2 x ushort8 per thread per tensor
  #pragma unroll
  for (int k = 0; k < 2; k++){
    int idx = t + k * 256;
    int r = idx >> 3, c8 = idx & 7;
    int grow = row0 + r;
    if (grow < M){
      *(u16x8*)&y0g[(size_t)grow * 64 + c8 * 8]  = *(const u16x8*)&Ys[r * YTS + c8 * 8];
      *(u16x8*)&re0g[(size_t)grow * 64 + c8 * 8] = *(const u16x8*)&Rs[r * YTS + c8 * 8];
    }
  }
}

// ---------------- layer-0 aggregation: 8 lanes/node (ushort8), unroll 8; h -> bf16 ----------------
__global__ void agg0_kernel(const unsigned short* __restrict__ y0,
                            const unsigned short* __restrict__ re0,
                            const float* __restrict__ bias0,
                            const int* __restrict__ rs, const int* __restrict__ deg,
                            const int* __restrict__ ssrc, unsigned short* __restrict__ h){
  int g = blockIdx.x * blockDim.x + threadIdx.x;
  if (g >= NN * 8) return;
  int node = g >> 3, lane = g & 7;
  int start = rs[node], cnt = deg[node];
  float acc[4][8] = {};
  int i = 0;
  for (; i + 8 <= cnt; i += 8){
    int s[8];
    #pragma unroll
    for (int j = 0; j < 8; j++) s[j] = ssrc[start + i + j];
    u16x8 v[8];
    #pragma unroll
    for (int j = 0; j < 8; j++) v[j] = *(const u16x8*)&y0[(size_t)s[j] * 64 + lane * 8];
    #pragma unroll
    for (int j = 0; j < 8; j++)
      #pragma unroll
      for (int k = 0; k < 8; k++) acc[j & 3][k] += bf2f((unsigned short)v[j][k]);
  }
  for (; i < cnt; i++){
    int s = ssrc[start + i];
    u16x8 v = *(const u16x8*)&y0[(size_t)s * 64 + lane * 8];
    #pragma unroll
    for (int k = 0; k < 8; k++) acc[0][k] += bf2f((unsigned short)v[k]);
  }
  float inv = 1.0f / (float)(cnt > 1 ? cnt : 1);
  u16x8 rv = *(const u16x8*)&re0[(size_t)node * 64 + lane * 8];
  float4 ba = ((const float4*)bias0)[lane * 2];
  float4 bb = ((const float4*)bias0)[lane * 2 + 1];
  float bv[8] = {ba.x, ba.y, ba.z, ba.w, bb.x, bb.y, bb.z, bb.w};
  u16x8 o;
  #pragma unroll
  for (int k = 0; k < 8; k++){
    float sum = (acc[0][k] + acc[1][k]) + (acc[2][k] + acc[3][k]);
    float x = sum * inv + bf2f((unsigned short)rv[k]) + bv[k];
    o[k] = f2bf(x > 0.f ? x : 0.f);
  }
  *(u16x8*)&h[(size_t)node * 64 + lane * 8] = o;
}

// ---- dual 16-col GEMM (bf16 H, E): Y1 = bf16(H@Wl1^T) ; Out = H@Wr1^T + E@wee^T + bl1 + b1e ----
__global__ __launch_bounds__(256) void gemm16_dual_kernel(
    const unsigned short* __restrict__ H, const unsigned short* __restrict__ E,
    const float* __restrict__ Wl1, const float* __restrict__ Wr1,
    const float* __restrict__ wee,
    const float* __restrict__ bl1, const float* __restrict__ b1e,
    unsigned short* __restrict__ Y1, float* __restrict__ Out, int M){
  __shared__ float Hs[64][65];
  __shared__ float Es[64][65];
  __shared__ float Wls[16][65];
  __shared__ float Wrs[16][65];
  __shared__ float Wes[16][65];
  __shared__ float bs[16];
  const int t = threadIdx.x;
  const int row0 = blockIdx.x * 64;
  {
    int j = t >> 4, kq = t & 15;
    float4 a = ((const float4*)Wl1)[j * 16 + kq];
    float4 b = ((const float4*)Wr1)[j * 16 + kq];
    float4 c = ((const float4*)wee)[j * 16 + kq];
    Wls[j][kq*4+0]=a.x; Wls[j][kq*4+1]=a.y; Wls[j][kq*4+2]=a.z; Wls[j][kq*4+3]=a.w;
    Wrs[j][kq*4+0]=b.x; Wrs[j][kq*4+1]=b.y; Wrs[j][kq*4+2]=b.z; Wrs[j][kq*4+3]=b.w;
    Wes[j][kq*4+0]=c.x; Wes[j][kq*4+1]=c.y; Wes[j][kq*4+2]=c.z; Wes[j][kq*4+3]=c.w;
  }
  if (t < 16) bs[t] = bl1[t] + b1e[t];
  for (int idx = t; idx < 64 * 16; idx += 256){
    int n = idx >> 4, kq = idx & 15;
    int row = row0 + n;
    ushort4 hv = make_ushort4(0,0,0,0), ev = make_ushort4(0,0,0,0);
    if (row < M){
      hv = *(const ushort4*)&H[(size_t)row * 64 + kq * 4];
      ev = *(const ushort4*)&E[(size_t)row * 64 + kq * 4];
    }
    Hs[n][kq*4+0]=bf2f(hv.x); Hs[n][kq*4+1]=bf2f(hv.y); Hs[n][kq*4+2]=bf2f(hv.z); Hs[n][kq*4+3]=bf2f(hv.w);
    Es[n][kq*4+0]=bf2f(ev.x); Es[n][kq*4+1]=bf2f(ev.y); Es[n][kq*4+2]=bf2f(ev.z); Es[n][kq*4+3]=bf2f(ev.w);
  }
  __syncthreads();
  const int n = t >> 2, jq = t & 3;
  float y[4] = {}, o[4] = {};
  #pragma unroll 4
  for (int k = 0; k < 64; k++){
    float a = Hs[n][k];
    float e = Es[n][k];
    #pragma unroll
    for (int j = 0; j < 4; j++){
      y[j] = fmaf(a, Wls[jq*4 + j][k], y[j]);
      o[j] = fmaf(a, Wrs[jq*4 + j][k], o[j]);
      o[j] = fmaf(e, Wes[jq*4 + j][k], o[j]);
    }
  }
  int row = row0 + n;
  if (row < M){
    ushort4 yb; yb.x = f2bf(y[0]); yb.y = f2bf(y[1]); yb.z = f2bf(y[2]); yb.w = f2bf(y[3]);
    *(ushort4*)&Y1[(size_t)row * 16 + jq * 4] = yb;
    ((float4*)Out)[(size_t)row * 4 + jq] =
        make_float4(o[0] + bs[jq*4+0], o[1] + bs[jq*4+1], o[2] + bs[jq*4+2], o[3] + bs[jq*4+3]);
  }
}

// ---------------- layer-1 aggregation: 2 lanes/node (ushort8), unroll 8 ----------------
__global__ void agg1_kernel(const unsigned short* __restrict__ y1,
                            const int* __restrict__ rs, const int* __restrict__ deg,
                            const int* __restrict__ ssrc, float* __restrict__ outp){
  int g = blockIdx.x * blockDim.x + threadIdx.x;
  if (g >= NN * 2) return;
  int node = g >> 1, lane = g & 1;
  int start = rs[node], cnt = deg[node];
  float acc[4][8] = {};
  int i = 0;
  for (; i + 8 <= cnt; i += 8){
    int s[8];
    #pragma unroll
    for (int j = 0; j < 8; j++) s[j] = ssrc[start + i + j];
    u16x8 v[8];
    #pragma unroll
    for (int j = 0; j < 8; j++) v[j] = *(const u16x8*)&y1[(size_t)s[j] * 16 + lane * 8];
    #pragma unroll
    for (int j = 0; j < 8; j++)
      #pragma unroll
      for (int k = 0; k < 8; k++) acc[j & 3][k] += bf2f((unsigned short)v[j][k]);
  }
  for (; i < cnt; i++){
    int s = ssrc[start + i];
    u16x8 v = *(const u16x8*)&y1[(size_t)s * 16 + lane * 8];
    #pragma unroll
    for (int k = 0; k < 8; k++) acc[0][k] += bf2f((unsigned short)v[k]);
  }
  float inv = 1.0f / (float)(cnt > 1 ? cnt : 1);
  f32x4 o0 = *(f32x4*)&outp[(size_t)node * 16 + lane * 8];
  f32x4 o1 = *(f32x4*)&outp[(size_t)node * 16 + lane * 8 + 4];
  #pragma unroll
  for (int k = 0; k < 4; k++){
    o0[k] += ((acc[0][k] + acc[1][k]) + (acc[2][k] + acc[3][k])) * inv;
    o1[k] += ((acc[0][k+4] + acc[1][k+4]) + (acc[2][k+4] + acc[3][k+4])) * inv;
  }
  *(f32x4*)&outp[(size_t)node * 16 + lane * 8]     = o0;
  *(f32x4*)&outp[(size_t)node * 16 + lane * 8 + 4] = o1;
}

extern "C" void kernel_launch(void* const* d_in, const int* in_sizes, int n_in,
                              void* d_out, int out_size, void* d_ws, size_t ws_size,
                              hipStream_t stream){
  (void)in_sizes; (void)n_in; (void)out_size; (void)ws_size;
  const float* x_feat = (const float*)d_in[0];
  const float* x_emb  = (const float*)d_in[1];
  const int*   ei     = (const int*)d_in[2];
  const float* Wl0 = (const float*)d_in[3];
  const float* bl0 = (const float*)d_in[4];
  const float* Wr0 = (const float*)d_in[5];
  const float* We0 = (const float*)d_in[6];
  const float* be0 = (const float*)d_in[7];
  const float* Wl1 = (const float*)d_in[8];
  const float* bl1 = (const float*)d_in[9];
  const float* Wr1 = (const float*)d_in[10];
  const float* We1 = (const float*)d_in[11];
  const float* be1 = (const float*)d_in[12];
  float* out = (float*)d_out;

  // workspace layout
  char* w = (char*)d_ws;
  unsigned short* re0 = (unsigned short*)w;  w += sizeof(unsigned short) * (size_t)NN * 64;
  unsigned short* h   = (unsigned short*)w;  w += sizeof(unsigned short) * (size_t)NN * 64;
  unsigned short* y0  = (unsigned short*)w;  w += sizeof(unsigned short) * (size_t)NN * 64;
  unsigned short* e_bf= (unsigned short*)w;  w += sizeof(unsigned short) * (size_t)NN * 64;
  unsigned short* y1  = (unsigned short*)w;  w += sizeof(unsigned short) * (size_t)NN * 16;
  unsigned short* wcat= (unsigned short*)w;  w += sizeof(unsigned short) * 128 * 192;
  float* wee   = (float*)w;                  w += sizeof(float) * 16 * 64;
  float* b1e   = (float*)w;                  w += sizeof(float) * 16;
  float* bias0 = (float*)w;                  w += sizeof(float) * 64;
  int* ebkt    = (int*)w;                    w += sizeof(int) * (size_t)NB * CAP;
  int* cur     = (int*)w;                    w += sizeof(int) * NB;
  int* rs      = (int*)w;                    w += sizeof(int) * NN;
  int* deg     = (int*)w;                    w += sizeof(int) * NN;

  const int* srcp = ei;
  const int* dstp = ei + EE;

  prep_all_kernel<<<ceil_div(PRE_N, 256), 256, 0, stream>>>(
      Wl0, Wr0, We0, bl0, be0, We1, be1, wcat, wee, b1e, bias0, cur);

  // edge build: bucket scatter -> in-place per-bucket sort -> padded CSR
  escatter_kernel<<<NCH, 256, 0, stream>>>(srcp, dstp, cur, ebkt);
  bsort_kernel<<<NB, 256, 0, stream>>>(cur, ebkt, rs, deg);

  // layer 0: y0 = bf16(x@Wl0^T), re0 = bf16(x@Wr0^T + e@We0^T), e_bf = bf16(e)
  l0_gemm_kernel<<<ceil_div(NN, 64), 256, 0, stream>>>(x_feat, x_emb, wcat, y0, re0, e_bf, NN);

  // h = bf16(relu(agg(y0)/deg + re0 + bias0))
  agg0_kernel<<<ceil_div(NN * 8, 256), 256, 0, stream>>>(
      y0, re0, bias0, rs, deg, ebkt, h);

  // layer 1: y1 = bf16(h@Wl1^T) ; out = h@Wr1^T + e@wee^T + bl1 + b1e
  gemm16_dual_kernel<<<ceil_div(NN, 64), 256, 0, stream>>>(h, e_bf, Wl1, Wr1, wee,
                                                           bl1, b1e, y1, out, NN);
  agg1_kernel<<<ceil_div(NN * 2, 256), 256, 0, stream>>>(y1, rs, deg, ebkt, out);
}

// Round 9
// 310.211 us; speedup vs baseline: 1.0585x; 1.0585x over previous
//
#include <hip/hip_runtime.h>
#include <hip/hip_bf16.h>
#include <cstddef>

#define NN 100000
#define EE 1600000
#define NPB 128                 // nodes per bucket
#define NB  782                 // ceil(NN / NPB)
#define ECH 4096                // edges per scatter chunk
#define NCH 391                 // ceil(EE / ECH)
#define CAP 4096                // bucket slot capacity (mean 2048, sigma ~45)

typedef __attribute__((ext_vector_type(8))) short bf16x8;
typedef __attribute__((ext_vector_type(8))) unsigned short u16x8;
typedef __attribute__((ext_vector_type(4))) float f32x4;

#define YTS 72                  // LDS ushort stride, y0 epilogue tile
#define RTS 68                  // LDS float stride, re0 epilogue tile

static inline int ceil_div(int a, int b){ return (a + b - 1) / b; }

__device__ inline unsigned short f2bf(float f){
  union { float f; unsigned u; } v; v.f = f;
  unsigned r = (v.u + 0x7fff + ((v.u >> 16) & 1)) >> 16;   // RNE
  return (unsigned short)r;
}
__device__ inline float bf2f(unsigned short s){
  union { unsigned u; float f; } v; v.u = ((unsigned)s) << 16;
  return v.f;
}

// ---- fused prep: wcat bf16, wee = We1@We0, b1e = We1@be0+be1, bias0 = bl0+be0, cur = 0 ----
#define PRE_W (128 * 192)
#define PRE_E (PRE_W + 16 * 64)
#define PRE_B (PRE_E + 16)
#define PRE_C (PRE_B + 64)
#define PRE_N (PRE_C + NB)
__global__ void prep_all_kernel(const float* __restrict__ Wl0, const float* __restrict__ Wr0,
                                const float* __restrict__ We0, const float* __restrict__ bl0,
                                const float* __restrict__ be0, const float* __restrict__ We1,
                                const float* __restrict__ be1,
                                unsigned short* __restrict__ wcat, float* __restrict__ wee,
                                float* __restrict__ b1e, float* __restrict__ bias0,
                                int* __restrict__ cur){
  int idx = blockIdx.x * blockDim.x + threadIdx.x;
  if (idx < PRE_W){
    int n = idx / 192, k = idx % 192;
    float v;
    if (n < 64) v = (k < 128) ? Wl0[n * 128 + k] : 0.f;
    else        v = (k < 128) ? Wr0[(n - 64) * 128 + k] : We0[(n - 64) * 64 + (k - 128)];
    wcat[idx] = f2bf(v);
  } else if (idx < PRE_E){
    int j = idx - PRE_W;
    int i = j >> 6, c = j & 63;
    float s = 0.f;
    for (int k = 0; k < 64; k++) s += We1[i * 64 + k] * We0[k * 64 + c];
    wee[j] = s;
  } else if (idx < PRE_B){
    int i = idx - PRE_E;
    float s = be1[i];
    for (int k = 0; k < 64; k++) s += We1[i * 64 + k] * be0[k];
    b1e[i] = s;
  } else if (idx < PRE_C){
    int i = idx - PRE_B;
    bias0[i] = bl0[i] + be0[i];
  } else if (idx < PRE_N){
    cur[idx - PRE_C] = 0;
  }
}

// ---------------- xprep: xb bf16 [N,192] = [x_feat | mean(x_emb)] ----------------
__global__ void xprep_kernel(const float* __restrict__ xf, const float* __restrict__ xe,
                             unsigned short* __restrict__ xb){
  int g = blockIdx.x * blockDim.x + threadIdx.x;   // N*24 octs
  if (g >= NN * 24) return;
  int node = g / 24, c8 = g % 24;
  u16x8 o;
  if (c8 < 16){
    float4 a = ((const float4*)xf)[(size_t)node * 32 + c8 * 2];
    float4 b = ((const float4*)xf)[(size_t)node * 32 + c8 * 2 + 1];
    o[0]=f2bf(a.x); o[1]=f2bf(a.y); o[2]=f2bf(a.z); o[3]=f2bf(a.w);
    o[4]=f2bf(b.x); o[5]=f2bf(b.y); o[6]=f2bf(b.z); o[7]=f2bf(b.w);
  } else {
    int q = c8 - 16;                                // emb oct 0..7
    float4 a0 = ((const float4*)xe)[(size_t)node * 32 + q * 2];
    float4 a1 = ((const float4*)xe)[(size_t)node * 32 + q * 2 + 1];
    float4 b0 = ((const float4*)xe)[(size_t)node * 32 + 16 + q * 2];
    float4 b1 = ((const float4*)xe)[(size_t)node * 32 + 16 + q * 2 + 1];
    o[0]=f2bf(0.5f*(a0.x+b0.x)); o[1]=f2bf(0.5f*(a0.y+b0.y));
    o[2]=f2bf(0.5f*(a0.z+b0.z)); o[3]=f2bf(0.5f*(a0.w+b0.w));
    o[4]=f2bf(0.5f*(a1.x+b1.x)); o[5]=f2bf(0.5f*(a1.y+b1.y));
    o[6]=f2bf(0.5f*(a1.z+b1.z)); o[7]=f2bf(0.5f*(a1.w+b1.w));
  }
  *(u16x8*)&xb[(size_t)node * 192 + c8 * 8] = o;
}

// ---------------- bucketed edge scatter (single dst pass, 16 cached in VGPRs) ----------------
__global__ __launch_bounds__(256) void escatter_kernel(const int* __restrict__ src,
                                                       const int* __restrict__ dst,
                                                       int* __restrict__ cur,
                                                       int* __restrict__ ebkt){
  __shared__ int lh[NB];
  __shared__ int lo[NB];
  int t = threadIdx.x;
  int e0 = blockIdx.x * ECH;
  int ne = EE - e0; if (ne > ECH) ne = ECH;
  for (int i = t; i < NB; i += 256) lh[i] = 0;
  __syncthreads();
  int dl[16];
  #pragma unroll
  for (int k = 0; k < 16; k++){
    int i = t + k * 256;
    dl[k] = (i < ne) ? dst[e0 + i] : -1;
  }
  #pragma unroll
  for (int k = 0; k < 16; k++)
    if (dl[k] >= 0) atomicAdd(&lh[dl[k] >> 7], 1);
  __syncthreads();
  for (int i = t; i < NB; i += 256){
    int c = lh[i];
    lo[i] = c ? atomicAdd(&cur[i], c) : 0;
    lh[i] = 0;
  }
  __syncthreads();
  #pragma unroll
  for (int k = 0; k < 16; k++){
    int i = t + k * 256;
    if (dl[k] >= 0){
      int d = dl[k], b = d >> 7;
      int r = atomicAdd(&lh[b], 1);
      int p = lo[b] + r;
      if (p < CAP) ebkt[b * CAP + p] = ((d & 127) << 24) | src[e0 + i];
    }
  }
}

// ---------------- per-bucket counting sort (in-place) -> padded CSR ----------------
__global__ __launch_bounds__(256) void bsort_kernel(
    const int* __restrict__ cur, int* __restrict__ ebkt,
    int* __restrict__ rs, int* __restrict__ deg){
  __shared__ int lraw[CAP];
  __shared__ int lout[CAP];
  __shared__ int lh[NPB];
  __shared__ int loff[NPB];
  __shared__ int lcur[NPB];
  const int t = threadIdx.x;
  const int b = blockIdx.x;
  const int e0 = b * CAP;
  int cnt = cur[b];
  if (cnt > CAP) cnt = CAP;
  for (int i = t; i < NPB; i += 256) lh[i] = 0;
  __syncthreads();
  for (int i = t; i < cnt; i += 256){
    int w = ebkt[e0 + i];
    lraw[i] = w;
    atomicAdd(&lh[((unsigned)w) >> 24], 1);
  }
  __syncthreads();
  {
    int v = (t < NPB) ? lh[t] : 0;
    int s = v;
    for (int off = 1; off < NPB; off <<= 1){
      int x = 0;
      if (t < NPB && t >= off) x = loff[t - off];
      __syncthreads();
      if (t < NPB) loff[t] = s;
      __syncthreads();
      if (t < NPB && t >= off) s += loff[t - off];
      __syncthreads();
    }
    if (t < NPB){ loff[t] = s - v; lcur[t] = s - v; }
  }
  __syncthreads();
  for (int i = t; i < cnt; i += 256){
    int w = lraw[i];
    int d = ((unsigned)w) >> 24;
    int pos = atomicAdd(&lcur[d], 1);
    lout[pos] = w & 0xFFFFFF;
  }
  __syncthreads();
  for (int i = t; i < cnt; i += 256) ebkt[e0 + i] = lout[i];
  if (t < NPB){
    int node = b * NPB + t;
    if (node < NN){
      rs[node]  = e0 + loff[t];
      deg[node] = lh[t];
    }
  }
}

// ---------------- layer-0 MFMA GEMM from pre-converted xb ----------------
// A = xb rows (64 x 192 bf16, 6 ushort8 loads/thread); Wcat 128x192 bf16.
// wave w: y0 cols w*16..+15 (bf16), re0 cols w*16..+15 (fp32). r7-style epilogue.
__global__ __launch_bounds__(256, 3) void l0_gemm_kernel(
    const unsigned short* __restrict__ xb, const unsigned short* __restrict__ wcat,
    unsigned short* __restrict__ y0g, float* __restrict__ re0g, int M){
  __shared__ unsigned short As[64 * 200];       // 25.6 KB
  __shared__ unsigned short Ys[64 * YTS];       // 9.2 KB
  __shared__ float          Rs[64 * RTS];       // 17.4 KB
  const int t = threadIdx.x;
  const int row0 = blockIdx.x * 64;
  // ---- staging: 6 ushort8 per thread (trivial register pressure -> fully batched) ----
  u16x8 tmp[6];
  #pragma unroll
  for (int k = 0; k < 6; k++){
    int idx = t + k * 256;
    int r = idx / 24, q = idx % 24;
    int row = row0 + r;
    u16x8 z = {0,0,0,0,0,0,0,0};
    tmp[k] = (row < M) ? *(const u16x8*)&xb[(size_t)row * 192 + q * 8] : z;
  }
  #pragma unroll
  for (int k = 0; k < 6; k++){
    int idx = t + k * 256;
    int r = idx / 24, q = idx % 24;
    *(u16x8*)&As[r * 200 + q * 8] = tmp[k];
  }
  // ---- B fragments (reg-resident, uniform across waves) ----
  const int w = t >> 6, l = t & 63;
  const int lm = l & 15, quad = l >> 4;
  bf16x8 bfr0[6], bfr1[6];
  {
    int n0 = w * 16 + lm;          // y0 tile w
    int n1 = 64 + w * 16 + lm;     // re0 tile w
    #pragma unroll
    for (int ks = 0; ks < 6; ks++){
      bfr0[ks] = *(const bf16x8*)&wcat[n0 * 192 + ks * 32 + quad * 8];
      bfr1[ks] = *(const bf16x8*)&wcat[n1 * 192 + ks * 32 + quad * 8];
    }
  }
  __syncthreads();
  for (int rg = 0; rg < 4; rg++){
    bf16x8 af[6];
    #pragma unroll
    for (int ks = 0; ks < 6; ks++)
      af[ks] = *(const bf16x8*)&As[(rg * 16 + lm) * 200 + ks * 32 + quad * 8];
    f32x4 acc0 = {0.f, 0.f, 0.f, 0.f};
    f32x4 acc1 = {0.f, 0.f, 0.f, 0.f};
    #pragma unroll
    for (int ks = 0; ks < 6; ks++){
      acc0 = __builtin_amdgcn_mfma_f32_16x16x32_bf16(af[ks], bfr0[ks], acc0, 0, 0, 0);
      acc1 = __builtin_amdgcn_mfma_f32_16x16x32_bf16(af[ks], bfr1[ks], acc1, 0, 0, 0);
    }
    // deposit C fragments (col=lm, row=quad*4+r)
    #pragma unroll
    for (int r = 0; r < 4; r++){
      int lrow = rg * 16 + quad * 4 + r;
      Ys[lrow * YTS + w * 16 + lm] = f2bf(acc0[r]);
      Rs[lrow * RTS + w * 16 + lm] = acc1[r];
    }
  }
  __syncthreads();
  // coalesced writeback: y0 ushort8 x2, re0 float4 x4
  #pragma unroll
  for (int k = 0; k < 2; k++){
    int idx = t + k * 256;
    int r = idx >> 3, c8 = idx & 7;
    int grow = row0 + r;
    if (grow < M)
      *(u16x8*)&y0g[(size_t)grow * 64 + c8 * 8] = *(const u16x8*)&Ys[r * YTS + c8 * 8];
  }
  #pragma unroll
  for (int k = 0; k < 4; k++){
    int idx = t + k * 256;
    int r = idx >> 4, c4 = idx & 15;
    int grow = row0 + r;
    if (grow < M)
      *(f32x4*)&re0g[(size_t)grow * 64 + c4 * 4] = *(const f32x4*)&Rs[r * RTS + c4 * 4];
  }
}

// ---------------- layer-0 aggregation: 8 lanes/node (ushort8), unroll 8; h -> bf16 ----------------
__global__ void agg0_kernel(const unsigned short* __restrict__ y0,
                            const float* __restrict__ re0,
                            const float* __restrict__ bias0,
                            const int* __restrict__ rs, const int* __restrict__ deg,
                            const int* __restrict__ ssrc, unsigned short* __restrict__ h){
  int g = blockIdx.x * blockDim.x + threadIdx.x;
  if (g >= NN * 8) return;
  int node = g >> 3, lane = g & 7;
  int start = rs[node], cnt = deg[node];
  float acc[4][8] = {};
  int i = 0;
  for (; i + 8 <= cnt; i += 8){
    int s[8];
    #pragma unroll
    for (int j = 0; j < 8; j++) s[j] = ssrc[start + i + j];
    u16x8 v[8];
    #pragma unroll
    for (int j = 0; j < 8; j++) v[j] = *(const u16x8*)&y0[(size_t)s[j] * 64 + lane * 8];
    #pragma unroll
    for (int j = 0; j < 8; j++)
      #pragma unroll
      for (int k = 0; k < 8; k++) acc[j & 3][k] += bf2f((unsigned short)v[j][k]);
  }
  for (; i < cnt; i++){
    int s = ssrc[start + i];
    u16x8 v = *(const u16x8*)&y0[(size_t)s * 64 + lane * 8];
    #pragma unroll
    for (int k = 0; k < 8; k++) acc[0][k] += bf2f((unsigned short)v[k]);
  }
  float inv = 1.0f / (float)(cnt > 1 ? cnt : 1);
  f32x4 rv0 = *(const f32x4*)&re0[(size_t)node * 64 + lane * 8];
  f32x4 rv1 = *(const f32x4*)&re0[(size_t)node * 64 + lane * 8 + 4];
  float rvv[8] = {rv0[0], rv0[1], rv0[2], rv0[3], rv1[0], rv1[1], rv1[2], rv1[3]};
  float4 ba = ((const float4*)bias0)[lane * 2];
  float4 bb = ((const float4*)bias0)[lane * 2 + 1];
  float bv[8] = {ba.x, ba.y, ba.z, ba.w, bb.x, bb.y, bb.z, bb.w};
  u16x8 o;
  #pragma unroll
  for (int k = 0; k < 8; k++){
    float sum = (acc[0][k] + acc[1][k]) + (acc[2][k] + acc[3][k]);
    float x = sum * inv + rvv[k] + bv[k];
    o[k] = f2bf(x > 0.f ? x : 0.f);
  }
  *(u16x8*)&h[(size_t)node * 64 + lane * 8] = o;
}

// ---- dual 16-col GEMM (bf16 H; E = xb cols 128..191): Y1 = bf16(H@Wl1^T) ; Out = H@Wr1^T + E@wee^T + bias ----
__global__ __launch_bounds__(256) void gemm16_dual_kernel(
    const unsigned short* __restrict__ H, const unsigned short* __restrict__ xb,
    const float* __restrict__ Wl1, const float* __restrict__ Wr1,
    const float* __restrict__ wee,
    const float* __restrict__ bl1, const float* __restrict__ b1e,
    unsigned short* __restrict__ Y1, float* __restrict__ Out, int M){
  __shared__ float Hs[64][65];
  __shared__ float Es[64][65];
  __shared__ float Wls[16][65];
  __shared__ float Wrs[16][65];
  __shared__ float Wes[16][65];
  __shared__ float bs[16];
  const int t = threadIdx.x;
  const int row0 = blockIdx.x * 64;
  {
    int j = t >> 4, kq = t & 15;
    float4 a = ((const float4*)Wl1)[j * 16 + kq];
    float4 b = ((const float4*)Wr1)[j * 16 + kq];
    float4 c = ((const float4*)wee)[j * 16 + kq];
    Wls[j][kq*4+0]=a.x; Wls[j][kq*4+1]=a.y; Wls[j][kq*4+2]=a.z; Wls[j][kq*4+3]=a.w;
    Wrs[j][kq*4+0]=b.x; Wrs[j][kq*4+1]=b.y; Wrs[j][kq*4+2]=b.z; Wrs[j][kq*4+3]=b.w;
    Wes[j][kq*4+0]=c.x; Wes[j][kq*4+1]=c.y; Wes[j][kq*4+2]=c.z; Wes[j][kq*4+3]=c.w;
  }
  if (t < 16) bs[t] = bl1[t] + b1e[t];
  for (int idx = t; idx < 64 * 16; idx += 256){
    int n = idx >> 4, kq = idx & 15;
    int row = row0 + n;
    ushort4 hv = make_ushort4(0,0,0,0), ev = make_ushort4(0,0,0,0);
    if (row < M){
      hv = *(const ushort4*)&H[(size_t)row * 64 + kq * 4];
      ev = *(const ushort4*)&xb[(size_t)row * 192 + 128 + kq * 4];
    }
    Hs[n][kq*4+0]=bf2f(hv.x); Hs[n][kq*4+1]=bf2f(hv.y); Hs[n][kq*4+2]=bf2f(hv.z); Hs[n][kq*4+3]=bf2f(hv.w);
    Es[n][kq*4+0]=bf2f(ev.x); Es[n][kq*4+1]=bf2f(ev.y); Es[n][kq*4+2]=bf2f(ev.z); Es[n][kq*4+3]=bf2f(ev.w);
  }
  __syncthreads();
  const int n = t >> 2, jq = t & 3;
  float y[4] = {}, o[4] = {};
  #pragma unroll 4
  for (int k = 0; k < 64; k++){
    float a = Hs[n][k];
    float e = Es[n][k];
    #pragma unroll
    for (int j = 0; j < 4; j++){
      y[j] = fmaf(a, Wls[jq*4 + j][k], y[j]);
      o[j] = fmaf(a, Wrs[jq*4 + j][k], o[j]);
      o[j] = fmaf(e, Wes[jq*4 + j][k], o[j]);
    }
  }
  int row = row0 + n;
  if (row < M){
    ushort4 yb; yb.x = f2bf(y[0]); yb.y = f2bf(y[1]); yb.z = f2bf(y[2]); yb.w = f2bf(y[3]);
    *(ushort4*)&Y1[(size_t)row * 16 + jq * 4] = yb;
    ((float4*)Out)[(size_t)row * 4 + jq] =
        make_float4(o[0] + bs[jq*4+0], o[1] + bs[jq*4+1], o[2] + bs[jq*4+2], o[3] + bs[jq*4+3]);
  }
}

// ---------------- layer-1 aggregation: 2 lanes/node (ushort8), unroll 8 ----------------
__global__ void agg1_kernel(const unsigned short* __restrict__ y1,
                            const int* __restrict__ rs, const int* __restrict__ deg,
                            const int* __restrict__ ssrc, float* __restrict__ outp){
  int g = blockIdx.x * blockDim.x + threadIdx.x;
  if (g >= NN * 2) return;
  int node = g >> 1, lane = g & 1;
  int start = rs[node], cnt = deg[node];
  float acc[4][8] = {};
  int i = 0;
  for (; i + 8 <= cnt; i += 8){
    int s[8];
    #pragma unroll
    for (int j = 0; j < 8; j++) s[j] = ssrc[start + i + j];
    u16x8 v[8];
    #pragma unroll
    for (int j = 0; j < 8; j++) v[j] = *(const u16x8*)&y1[(size_t)s[j] * 16 + lane * 8];
    #pragma unroll
    for (int j = 0; j < 8; j++)
      #pragma unroll
      for (int k = 0; k < 8; k++) acc[j & 3][k] += bf2f((unsigned short)v[j][k]);
  }
  for (; i < cnt; i++){
    int s = ssrc[start + i];
    u16x8 v = *(const u16x8*)&y1[(size_t)s * 16 + lane * 8];
    #pragma unroll
    for (int k = 0; k < 8; k++) acc[0][k] += bf2f((unsigned short)v[k]);
  }
  float inv = 1.0f / (float)(cnt > 1 ? cnt : 1);
  f32x4 o0 = *(f32x4*)&outp[(size_t)node * 16 + lane * 8];
  f32x4 o1 = *(f32x4*)&outp[(size_t)node * 16 + lane * 8 + 4];
  #pragma unroll
  for (int k = 0; k < 4; k++){
    o0[k] += ((acc[0][k] + acc[1][k]) + (acc[2][k] + acc[3][k])) * inv;
    o1[k] += ((acc[0][k+4] + acc[1][k+4]) + (acc[2][k+4] + acc[3][k+4])) * inv;
  }
  *(f32x4*)&outp[(size_t)node * 16 + lane * 8]     = o0;
  *(f32x4*)&outp[(size_t)node * 16 + lane * 8 + 4] = o1;
}

extern "C" void kernel_launch(void* const* d_in, const int* in_sizes, int n_in,
                              void* d_out, int out_size, void* d_ws, size_t ws_size,
                              hipStream_t stream){
  (void)in_sizes; (void)n_in; (void)out_size; (void)ws_size;
  const float* x_feat = (const float*)d_in[0];
  const float* x_emb  = (const float*)d_in[1];
  const int*   ei     = (const int*)d_in[2];
  const float* Wl0 = (const float*)d_in[3];
  const float* bl0 = (const float*)d_in[4];
  const float* Wr0 = (const float*)d_in[5];
  const float* We0 = (const float*)d_in[6];
  const float* be0 = (const float*)d_in[7];
  const float* Wl1 = (const float*)d_in[8];
  const float* bl1 = (const float*)d_in[9];
  const float* Wr1 = (const float*)d_in[10];
  const float* We1 = (const float*)d_in[11];
  const float* be1 = (const float*)d_in[12];
  float* out = (float*)d_out;

  // workspace layout (~106 MB)
  char* w = (char*)d_ws;
  float* re0          = (float*)w;           w += sizeof(float) * (size_t)NN * 64;
  unsigned short* xb  = (unsigned short*)w;  w += sizeof(unsigned short) * (size_t)NN * 192;
  unsigned short* h   = (unsigned short*)w;  w += sizeof(unsigned short) * (size_t)NN * 64;
  unsigned short* y0  = (unsigned short*)w;  w += sizeof(unsigned short) * (size_t)NN * 64;
  unsigned short* y1  = (unsigned short*)w;  w += sizeof(unsigned short) * (size_t)NN * 16;
  unsigned short* wcat= (unsigned short*)w;  w += sizeof(unsigned short) * 128 * 192;
  float* wee   = (float*)w;                  w += sizeof(float) * 16 * 64;
  float* b1e   = (float*)w;                  w += sizeof(float) * 16;
  float* bias0 = (float*)w;                  w += sizeof(float) * 64;
  int* ebkt    = (int*)w;                    w += sizeof(int) * (size_t)NB * CAP;
  int* cur     = (int*)w;                    w += sizeof(int) * NB;
  int* rs      = (int*)w;                    w += sizeof(int) * NN;
  int* deg     = (int*)w;                    w += sizeof(int) * NN;

  const int* srcp = ei;
  const int* dstp = ei + EE;

  prep_all_kernel<<<ceil_div(PRE_N, 256), 256, 0, stream>>>(
      Wl0, Wr0, We0, bl0, be0, We1, be1, wcat, wee, b1e, bias0, cur);

  // xb = bf16([x_feat | mean(x_emb)])  (pure streaming)
  xprep_kernel<<<ceil_div(NN * 24, 256), 256, 0, stream>>>(x_feat, x_emb, xb);

  // edge build: bucket scatter -> in-place per-bucket sort -> padded CSR
  escatter_kernel<<<NCH, 256, 0, stream>>>(srcp, dstp, cur, ebkt);
  bsort_kernel<<<NB, 256, 0, stream>>>(cur, ebkt, rs, deg);

  // layer 0: y0 = bf16(x@Wl0^T), re0 = x@Wr0^T + e@We0^T
  l0_gemm_kernel<<<ceil_div(NN, 64), 256, 0, stream>>>(xb, wcat, y0, re0, NN);

  // h = bf16(relu(agg(y0)/deg + re0 + bias0))
  agg0_kernel<<<ceil_div(NN * 8, 256), 256, 0, stream>>>(
      y0, re0, bias0, rs, deg, ebkt, h);

  // layer 1: y1 = bf16(h@Wl1^T) ; out = h@Wr1^T + e@wee^T + bl1 + b1e
  gemm16_dual_kernel<<<ceil_div(NN, 64), 256, 0, stream>>>(h, xb, Wl1, Wr1, wee,
                                                           bl1, b1e, y1, out, NN);
  agg1_kernel<<<ceil_div(NN * 2, 256), 256, 0, stream>>>(y1, rs, deg, ebkt, out);
}